// Round 3
// baseline (989.363 us; speedup 1.0000x reference)
//
#include <hip/hip_runtime.h>
#include <math.h>

#define BB   4096
#define KK   200
#define DD   128
#define FDIM 1024
#define MASK_FILL (-4294967295.0f)   // -(2^32)+1, as fp32

// One block per batch row b. Fuses target = W @ tf[b] (redundant per block,
// hidden under the nf HBM loads), masked softmax, and both weighted sums.
// Thread layout: c4 = tid&31 owns d-chunk [4*c4, 4*c4+4); grp = tid>>5 owns
// k = grp + 16*i (13 per thread). nf held in registers (52 VGPR).
__global__ __launch_bounds__(512, 4) void fused_attn(const float* __restrict__ tf,
                                                     const float* __restrict__ nf,
                                                     const float* __restrict__ nl,
                                                     const int*   __restrict__ mask,
                                                     const float* __restrict__ W,
                                                     float* __restrict__ out) {
    __shared__ __align__(16) float s_tgt[DD];
    __shared__ float  s_alpha[KK];
    __shared__ float  s_stat[2];
    __shared__ float4 s_rn[16][32];
    __shared__ float4 s_rl[16][32];

    const int tid = threadIdx.x;
    const int b   = blockIdx.x;
    const int c4  = tid & 31;
    const int grp = tid >> 5;

    const float4* nf4 = (const float4*)(nf + (size_t)b * KK * DD);
    const float4* nl4 = (const float4*)(nl + (size_t)b * KK * DD);
    const int*    mb  = mask + (size_t)b * KK;

    // ---- Phase 0: issue all neighbor_feats loads (latency hidden by W-compute)
    float4 vnf[13];
    #pragma unroll
    for (int i = 0; i < 13; ++i) {
        const int k = grp + 16 * i;
        if (k < KK) vnf[i] = nf4[k * 32 + c4];
    }

    // ---- Phase 1: target[d] for d = grp*8+dj, partial over f = 4*c4 + 128*i.
    // W loads are lane-consecutive (coalesced, L2-resident: W = 512 KiB).
    {
        const float4* tf4 = (const float4*)(tf + (size_t)b * FDIM);
        const float4* W4  = (const float4*)W;
        float acc[8] = {0, 0, 0, 0, 0, 0, 0, 0};
        #pragma unroll
        for (int i = 0; i < 8; ++i) {
            const float4 t = tf4[c4 + 32 * i];
            #pragma unroll
            for (int dj = 0; dj < 8; ++dj) {
                const float4 w = W4[(grp * 8 + dj) * (FDIM / 4) + c4 + 32 * i];
                acc[dj] += w.x * t.x + w.y * t.y + w.z * t.z + w.w * t.w;
            }
        }
        #pragma unroll
        for (int dj = 0; dj < 8; ++dj) {
            float v = acc[dj];
            #pragma unroll
            for (int off = 16; off > 0; off >>= 1)
                v += __shfl_xor(v, off);
            if (c4 == 0) s_tgt[grp * 8 + dj] = v;
        }
    }
    __syncthreads();

    // ---- Phase 2: alpha[k] = <nf[k,:], target>, masked
    const float4 tg = ((const float4*)s_tgt)[c4];
    #pragma unroll
    for (int i = 0; i < 13; ++i) {
        const int k = grp + 16 * i;
        if (k < KK) {
            float d = vnf[i].x * tg.x + vnf[i].y * tg.y + vnf[i].z * tg.z + vnf[i].w * tg.w;
            #pragma unroll
            for (int off = 16; off > 0; off >>= 1)
                d += __shfl_xor(d, off);
            if (c4 == 0)
                s_alpha[k] = (mb[k] > 0) ? d : MASK_FILL;
        }
    }
    __syncthreads();

    // ---- Phase 3: softmax stats (wave 0 only)
    if (tid < 64) {
        float m = -INFINITY;
        for (int k = tid; k < KK; k += 64) m = fmaxf(m, s_alpha[k]);
        #pragma unroll
        for (int off = 32; off > 0; off >>= 1)
            m = fmaxf(m, __shfl_xor(m, off));
        float s = 0.0f;
        for (int k = tid; k < KK; k += 64) s += __expf(s_alpha[k] - m);
        #pragma unroll
        for (int off = 32; off > 0; off >>= 1)
            s += __shfl_xor(s, off);
        if (tid == 0) { s_stat[0] = m; s_stat[1] = s; }
    }
    __syncthreads();

    // ---- Phase 4: weighted sums; nf from regs, nl streamed once, p recomputed
    const float m  = s_stat[0];
    const float iv = 1.0f / s_stat[1];
    float4 an = {0, 0, 0, 0}, al = {0, 0, 0, 0};
    #pragma unroll
    for (int i = 0; i < 13; ++i) {
        const int k = grp + 16 * i;
        if (k < KK) {
            const float  p  = __expf(s_alpha[k] - m) * iv;
            const float4 vl = nl4[k * 32 + c4];
            an.x += p * vnf[i].x; an.y += p * vnf[i].y; an.z += p * vnf[i].z; an.w += p * vnf[i].w;
            al.x += p * vl.x;     al.y += p * vl.y;     al.z += p * vl.z;     al.w += p * vl.w;
        }
    }
    s_rn[grp][c4] = an;
    s_rl[grp][c4] = al;
    __syncthreads();

    // ---- Phase 5: final reduce over the 16 k-groups, write both outputs
    if (tid < 32) {
        float4 r = {0, 0, 0, 0};
        #pragma unroll
        for (int g = 0; g < 16; ++g) {
            float4 v = s_rn[g][tid];
            r.x += v.x; r.y += v.y; r.z += v.z; r.w += v.w;
        }
        ((float4*)(out + (size_t)b * DD))[tid] = r;
    } else if (tid < 64) {
        const int c = tid - 32;
        float4 r = {0, 0, 0, 0};
        #pragma unroll
        for (int g = 0; g < 16; ++g) {
            float4 v = s_rl[g][c];
            r.x += v.x; r.y += v.y; r.z += v.z; r.w += v.w;
        }
        ((float4*)(out + (size_t)BB * DD + (size_t)b * DD))[c] = r;
    }
}

extern "C" void kernel_launch(void* const* d_in, const int* in_sizes, int n_in,
                              void* d_out, int out_size, void* d_ws, size_t ws_size,
                              hipStream_t stream) {
    const float* tf   = (const float*)d_in[0];
    const float* nf   = (const float*)d_in[1];
    const float* nl   = (const float*)d_in[2];
    const int*   mask = (const int*)d_in[3];
    const float* W    = (const float*)d_in[4];
    float* out = (float*)d_out;

    fused_attn<<<BB, 512, 0, stream>>>(tf, nf, nl, mask, W, out);
}

// Round 4
// 624.467 us; speedup vs baseline: 1.5843x; 1.5843x over previous
//
#include <hip/hip_runtime.h>
#include <math.h>

#define BB   4096
#define KK   200
#define DD   128
#define FDIM 1024
#define MASK_FILL (-4294967295.0f)   // -(2^32)+1, as fp32

// One block per batch row b. Phase 1 computes target = W @ tf[b] in a scoped
// register set; only AFTER its barrier do we load nf into registers (13 float4).
// Softmax stats are computed redundantly per-wave (no serial wave-0 phase).
__global__ __launch_bounds__(512, 4) void fused_attn(const float* __restrict__ tf,
                                                     const float* __restrict__ nf,
                                                     const float* __restrict__ nl,
                                                     const int*   __restrict__ mask,
                                                     const float* __restrict__ W,
                                                     float* __restrict__ out) {
    __shared__ __align__(16) float s_tgt[DD];
    __shared__ float  s_alpha[KK];
    __shared__ float4 s_rn[16][32];
    __shared__ float4 s_rl[16][32];

    const int tid  = threadIdx.x;
    const int b    = blockIdx.x;
    const int c4   = tid & 31;    // d-chunk: floats 4*c4 .. 4*c4+3
    const int grp  = tid >> 5;    // k = grp + 16*i
    const int lane = tid & 63;

    const float4* nf4 = (const float4*)(nf + (size_t)b * KK * DD);
    const float4* nl4 = (const float4*)(nl + (size_t)b * KK * DD);
    const int*    mb  = mask + (size_t)b * KK;

    // ---- Phase 1: target[grp*8+dj] partials over f = 4*c4 + 128*i (scoped regs)
    {
        const float4* tf4 = (const float4*)(tf + (size_t)b * FDIM);
        const float4* W4  = (const float4*)W;
        float acc[8] = {0, 0, 0, 0, 0, 0, 0, 0};
        #pragma unroll
        for (int i = 0; i < 8; ++i) {
            const float4 t = tf4[c4 + 32 * i];
            #pragma unroll
            for (int dj = 0; dj < 8; ++dj) {
                const float4 w = W4[(grp * 8 + dj) * (FDIM / 4) + c4 + 32 * i];
                acc[dj] += w.x * t.x + w.y * t.y + w.z * t.z + w.w * t.w;
            }
        }
        #pragma unroll
        for (int dj = 0; dj < 8; ++dj) {
            float v = acc[dj];
            #pragma unroll
            for (int off = 16; off > 0; off >>= 1)
                v += __shfl_xor(v, off);
            if (c4 == 0) s_tgt[grp * 8 + dj] = v;
        }
    }
    __syncthreads();   // publishes s_tgt; also fences the nf loads below out of phase 1

    // ---- Phase 2: load nf into regs, alpha (kept in registers, all lanes)
    const float4 tg = ((const float4*)s_tgt)[c4];
    float4 vnf[13];
    float  alpha_r[13];
    #pragma unroll
    for (int i = 0; i < 13; ++i) {
        const int k = grp + 16 * i;
        if (k < KK) vnf[i] = nf4[k * 32 + c4];
    }
    #pragma unroll
    for (int i = 0; i < 13; ++i) {
        const int k = grp + 16 * i;
        if (k < KK) {
            float d = vnf[i].x * tg.x + vnf[i].y * tg.y + vnf[i].z * tg.z + vnf[i].w * tg.w;
            #pragma unroll
            for (int off = 16; off > 0; off >>= 1)
                d += __shfl_xor(d, off);
            d = (mb[k] > 0) ? d : MASK_FILL;
            alpha_r[i] = d;
            if (c4 == 0) s_alpha[k] = d;
        }
    }
    __syncthreads();

    // ---- Phase 3: softmax stats, computed redundantly by EVERY wave (no 2nd barrier)
    float m = -INFINITY;
    #pragma unroll
    for (int k = lane; k < KK; k += 64) m = fmaxf(m, s_alpha[k]);
    #pragma unroll
    for (int off = 32; off > 0; off >>= 1)
        m = fmaxf(m, __shfl_xor(m, off));
    float s = 0.0f;
    #pragma unroll
    for (int k = lane; k < KK; k += 64) s += __expf(s_alpha[k] - m);
    #pragma unroll
    for (int off = 32; off > 0; off >>= 1)
        s += __shfl_xor(s, off);
    const float iv = 1.0f / s;

    // ---- Phase 4: weighted sums; nf + alpha from regs, nl streamed once
    float4 an = {0, 0, 0, 0}, al = {0, 0, 0, 0};
    #pragma unroll
    for (int i = 0; i < 13; ++i) {
        const int k = grp + 16 * i;
        if (k < KK) {
            const float4 vl = nl4[k * 32 + c4];
            const float  p  = __expf(alpha_r[i] - m) * iv;
            an.x += p * vnf[i].x; an.y += p * vnf[i].y; an.z += p * vnf[i].z; an.w += p * vnf[i].w;
            al.x += p * vl.x;     al.y += p * vl.y;     al.z += p * vl.z;     al.w += p * vl.w;
        }
    }
    s_rn[grp][c4] = an;
    s_rl[grp][c4] = al;
    __syncthreads();

    // ---- Phase 5: final reduce over the 16 k-groups, write both outputs
    if (tid < 32) {
        float4 r = {0, 0, 0, 0};
        #pragma unroll
        for (int g = 0; g < 16; ++g) {
            float4 v = s_rn[g][tid];
            r.x += v.x; r.y += v.y; r.z += v.z; r.w += v.w;
        }
        ((float4*)(out + (size_t)b * DD))[tid] = r;
    } else if (tid < 64) {
        const int c = tid - 32;
        float4 r = {0, 0, 0, 0};
        #pragma unroll
        for (int g = 0; g < 16; ++g) {
            float4 v = s_rl[g][c];
            r.x += v.x; r.y += v.y; r.z += v.z; r.w += v.w;
        }
        ((float4*)(out + (size_t)BB * DD + (size_t)b * DD))[c] = r;
    }
}

extern "C" void kernel_launch(void* const* d_in, const int* in_sizes, int n_in,
                              void* d_out, int out_size, void* d_ws, size_t ws_size,
                              hipStream_t stream) {
    const float* tf   = (const float*)d_in[0];
    const float* nf   = (const float*)d_in[1];
    const float* nl   = (const float*)d_in[2];
    const int*   mask = (const int*)d_in[3];
    const float* W    = (const float*)d_in[4];
    float* out = (float*)d_out;

    fused_attn<<<BB, 512, 0, stream>>>(tf, nf, nl, mask, W, out);
}

// Round 5
// 353.327 us; speedup vs baseline: 2.8001x; 1.7674x over previous
//
#include <hip/hip_runtime.h>
#include <math.h>

#define BB   4096
#define KK   200
#define DD   128
#define FDIM 1024
#define MASK_FILL (-4294967295.0f)   // -(2^32)+1, as fp32

// One block per batch row b. Phase 1 computes target = W @ tf[b]; a
// sched_barrier(0) pins the phase boundary so the nf register loads cannot be
// hoisted into phase 1 (that hoist caused the round-3/4 VGPR spill).
__global__ __launch_bounds__(512) void fused_attn(const float* __restrict__ tf,
                                                  const float* __restrict__ nf,
                                                  const float* __restrict__ nl,
                                                  const int*   __restrict__ mask,
                                                  const float* __restrict__ W,
                                                  float* __restrict__ out) {
    __shared__ __align__(16) float s_tgt[DD];
    __shared__ float  s_alpha[KK];
    __shared__ float4 s_rn[16][32];
    __shared__ float4 s_rl[16][32];

    const int tid  = threadIdx.x;
    const int b    = blockIdx.x;
    const int c4   = tid & 31;    // d-chunk: floats 4*c4 .. 4*c4+3
    const int grp  = tid >> 5;    // k = grp + 16*i
    const int lane = tid & 63;

    const float4* nf4 = (const float4*)(nf + (size_t)b * KK * DD);
    const float4* nl4 = (const float4*)(nl + (size_t)b * KK * DD);
    const int*    mb  = mask + (size_t)b * KK;

    // ---- Phase 1: target[grp*8+dj], partials over f = 4*c4 + 128*i
    {
        const float4* tf4 = (const float4*)(tf + (size_t)b * FDIM);
        const float4* W4  = (const float4*)W;
        float acc[8] = {0, 0, 0, 0, 0, 0, 0, 0};
        #pragma unroll
        for (int i = 0; i < 8; ++i) {
            const float4 t = tf4[c4 + 32 * i];
            #pragma unroll
            for (int dj = 0; dj < 8; ++dj) {
                const float4 w = W4[(grp * 8 + dj) * (FDIM / 4) + c4 + 32 * i];
                acc[dj] += w.x * t.x + w.y * t.y + w.z * t.z + w.w * t.w;
            }
        }
        #pragma unroll
        for (int dj = 0; dj < 8; ++dj) {
            float v = acc[dj];
            #pragma unroll
            for (int off = 16; off > 0; off >>= 1)
                v += __shfl_xor(v, off);
            if (c4 == 0) s_tgt[grp * 8 + dj] = v;
        }
    }
    __syncthreads();
    __builtin_amdgcn_sched_barrier(0);   // hard fence: keep nf loads out of phase 1

    // ---- Phase 2: load nf into regs, alpha[k] = <nf[k,:], target>, masked
    const float4 tg = ((const float4*)s_tgt)[c4];
    float4 vnf[13];
    #pragma unroll
    for (int i = 0; i < 13; ++i) {
        const int k = grp + 16 * i;
        if (k < KK) vnf[i] = nf4[k * 32 + c4];
    }
    #pragma unroll
    for (int i = 0; i < 13; ++i) {
        const int k = grp + 16 * i;
        if (k < KK) {
            float d = vnf[i].x * tg.x + vnf[i].y * tg.y + vnf[i].z * tg.z + vnf[i].w * tg.w;
            #pragma unroll
            for (int off = 16; off > 0; off >>= 1)
                d += __shfl_xor(d, off);
            if (c4 == 0)
                s_alpha[k] = (mb[k] > 0) ? d : MASK_FILL;
        }
    }
    __syncthreads();

    // ---- Phase 3: softmax stats, redundantly per wave (no extra barrier)
    float m = -INFINITY;
    for (int k = lane; k < KK; k += 64) m = fmaxf(m, s_alpha[k]);
    #pragma unroll
    for (int off = 32; off > 0; off >>= 1)
        m = fmaxf(m, __shfl_xor(m, off));
    float s = 0.0f;
    for (int k = lane; k < KK; k += 64) s += __expf(s_alpha[k] - m);
    #pragma unroll
    for (int off = 32; off > 0; off >>= 1)
        s += __shfl_xor(s, off);
    const float iv = 1.0f / s;

    // ---- Phase 4: weighted sums; nf from regs, p via LDS broadcast, nl streamed
    float4 an = {0, 0, 0, 0}, al = {0, 0, 0, 0};
    #pragma unroll
    for (int i = 0; i < 13; ++i) {
        const int k = grp + 16 * i;
        if (k < KK) {
            const float4 vl = nl4[k * 32 + c4];
            const float  p  = __expf(s_alpha[k] - m) * iv;   // same addr across half-wave: broadcast
            an.x += p * vnf[i].x; an.y += p * vnf[i].y; an.z += p * vnf[i].z; an.w += p * vnf[i].w;
            al.x += p * vl.x;     al.y += p * vl.y;     al.z += p * vl.z;     al.w += p * vl.w;
        }
    }
    s_rn[grp][c4] = an;
    s_rl[grp][c4] = al;
    __syncthreads();

    // ---- Phase 5: final reduce over the 16 k-groups, write both outputs
    if (tid < 32) {
        float4 r = {0, 0, 0, 0};
        #pragma unroll
        for (int g = 0; g < 16; ++g) {
            float4 v = s_rn[g][tid];
            r.x += v.x; r.y += v.y; r.z += v.z; r.w += v.w;
        }
        ((float4*)(out + (size_t)b * DD))[tid] = r;
    } else if (tid < 64) {
        const int c = tid - 32;
        float4 r = {0, 0, 0, 0};
        #pragma unroll
        for (int g = 0; g < 16; ++g) {
            float4 v = s_rl[g][c];
            r.x += v.x; r.y += v.y; r.z += v.z; r.w += v.w;
        }
        ((float4*)(out + (size_t)BB * DD + (size_t)b * DD))[c] = r;
    }
}

extern "C" void kernel_launch(void* const* d_in, const int* in_sizes, int n_in,
                              void* d_out, int out_size, void* d_ws, size_t ws_size,
                              hipStream_t stream) {
    const float* tf   = (const float*)d_in[0];
    const float* nf   = (const float*)d_in[1];
    const float* nl   = (const float*)d_in[2];
    const int*   mask = (const int*)d_in[3];
    const float* W    = (const float*)d_in[4];
    float* out = (float*)d_out;

    fused_attn<<<BB, 512, 0, stream>>>(tf, nf, nl, mask, W, out);
}

// Round 7
// 234.858 us; speedup vs baseline: 4.2126x; 1.5044x over previous
//
#include <hip/hip_runtime.h>
#include <math.h>

#define BB   4096
#define KK   200
#define DD   128
#define FDIM 1024
#define MASK_FILL (-4294967295.0f)   // -(2^32)+1, as fp32

typedef float fx4 __attribute__((ext_vector_type(4)));   // native vec4 (nontemporal-compatible)

// ---------------- Kernel 1: target = target_feats @ W^T  ([B,FD] x [D,FD] -> [B,D])
// 512 blocks x 256 threads; 8 batch rows per block; FD split in half per thread.
__global__ __launch_bounds__(256) void target_gemm(const float* __restrict__ tf,
                                                   const float* __restrict__ W,
                                                   float* __restrict__ tgt) {
    __shared__ float s_tf[8 * FDIM];        // 32 KiB
    __shared__ float s_red[8][DD];          // 4 KiB
    const int tid = threadIdx.x;
    const int d   = tid & 127;
    const int h   = tid >> 7;               // 0/1: which half of FD (uniform per wave)
    const size_t r0 = (size_t)blockIdx.x * 8;

    const fx4* src = (const fx4*)(tf + r0 * FDIM);
    for (int i = tid; i < 8 * FDIM / 4; i += 256)
        ((fx4*)s_tf)[i] = src[i];
    __syncthreads();

    float acc[8] = {0, 0, 0, 0, 0, 0, 0, 0};
    const fx4* wr = (const fx4*)(W + (size_t)d * FDIM) + h * (FDIM / 8);
    #pragma unroll 4
    for (int i = 0; i < FDIM / 8; ++i) {
        fx4 w = wr[i];
        #pragma unroll
        for (int r = 0; r < 8; ++r) {
            fx4 t = ((const fx4*)(s_tf + r * FDIM + h * (FDIM / 2)))[i];  // wave-broadcast
            acc[r] += w.x * t.x + w.y * t.y + w.z * t.z + w.w * t.w;
        }
    }
    if (h == 1) {
        #pragma unroll
        for (int r = 0; r < 8; ++r) s_red[r][d] = acc[r];
    }
    __syncthreads();
    if (h == 0) {
        #pragma unroll
        for (int r = 0; r < 8; ++r)
            tgt[(r0 + r) * DD + d] = acc[r] + s_red[r][d];
    }
}

// ---------------- Kernel 2: masked-softmax attention, one block per b.
// No register-held nf: phase A streams nf once (alpha); phase C re-reads nf
// (Infinity-Cache hit: ~100-200 MB live working set < 256 MB L3) and streams
// nl with NONTEMPORAL loads so the once-read label data doesn't evict nf.
__global__ __launch_bounds__(512, 6) void attn(const float* __restrict__ nf,
                                               const float* __restrict__ nl,
                                               const int*   __restrict__ mask,
                                               const float* __restrict__ tgt,
                                               float* __restrict__ out) {
    __shared__ float s_alpha[KK];
    __shared__ fx4   s_rn[16][32];
    __shared__ fx4   s_rl[16][32];

    const int tid  = threadIdx.x;
    const int b    = blockIdx.x;
    const int c4   = tid & 31;    // d-chunk: floats 4*c4 .. 4*c4+3
    const int grp  = tid >> 5;    // k = grp + 16*i
    const int lane = tid & 63;

    const fx4* nf4 = (const fx4*)(nf + (size_t)b * KK * DD);
    const fx4* nl4 = (const fx4*)(nl + (size_t)b * KK * DD);
    const int* mb  = mask + (size_t)b * KK;

    // ---- Phase A: alpha[k] = <nf[k,:], target[b,:]>, masked (nf streamed, cached)
    {
        const fx4 tg = ((const fx4*)(tgt + (size_t)b * DD))[c4];
        #pragma unroll
        for (int i = 0; i < 13; ++i) {
            const int k = grp + 16 * i;
            if (k < KK) {
                const fx4 v = nf4[k * 32 + c4];
                float d = v.x * tg.x + v.y * tg.y + v.z * tg.z + v.w * tg.w;
                #pragma unroll
                for (int off = 16; off > 0; off >>= 1)
                    d += __shfl_xor(d, off);
                if (c4 == 0)
                    s_alpha[k] = (mb[k] > 0) ? d : MASK_FILL;
            }
        }
    }
    __syncthreads();

    // ---- Phase B: softmax stats, redundantly per wave (no extra barrier)
    float m = -INFINITY;
    for (int k = lane; k < KK; k += 64) m = fmaxf(m, s_alpha[k]);
    #pragma unroll
    for (int off = 32; off > 0; off >>= 1)
        m = fmaxf(m, __shfl_xor(m, off));
    float s = 0.0f;
    for (int k = lane; k < KK; k += 64) s += __expf(s_alpha[k] - m);
    #pragma unroll
    for (int off = 32; off > 0; off >>= 1)
        s += __shfl_xor(s, off);
    const float iv = 1.0f / s;

    // ---- Phase C: weighted sums; nf re-read (L3-resident), nl nontemporal
    fx4 an = {0, 0, 0, 0}, al = {0, 0, 0, 0};
    #pragma unroll
    for (int i = 0; i < 13; ++i) {
        const int k = grp + 16 * i;
        if (k < KK) {
            const float p  = __expf(s_alpha[k] - m) * iv;   // LDS broadcast + cheap exp
            const fx4   vn = nf4[k * 32 + c4];
            const fx4   vl = __builtin_nontemporal_load(&nl4[k * 32 + c4]);
            an += p * vn;
            al += p * vl;
        }
    }
    s_rn[grp][c4] = an;
    s_rl[grp][c4] = al;
    __syncthreads();

    // ---- Phase D: final reduce over the 16 k-groups, nontemporal output writes
    if (tid < 32) {
        fx4 r = {0, 0, 0, 0};
        #pragma unroll
        for (int g = 0; g < 16; ++g) r += s_rn[g][tid];
        __builtin_nontemporal_store(r, &((fx4*)(out + (size_t)b * DD))[tid]);
    } else if (tid < 64) {
        const int c = tid - 32;
        fx4 r = {0, 0, 0, 0};
        #pragma unroll
        for (int g = 0; g < 16; ++g) r += s_rl[g][c];
        __builtin_nontemporal_store(r, &((fx4*)(out + (size_t)BB * DD + (size_t)b * DD))[c]);
    }
}

extern "C" void kernel_launch(void* const* d_in, const int* in_sizes, int n_in,
                              void* d_out, int out_size, void* d_ws, size_t ws_size,
                              hipStream_t stream) {
    const float* tf   = (const float*)d_in[0];
    const float* nf   = (const float*)d_in[1];
    const float* nl   = (const float*)d_in[2];
    const int*   mask = (const int*)d_in[3];
    const float* W    = (const float*)d_in[4];
    float* out = (float*)d_out;
    float* tgt = (float*)d_ws;                 // B*D*4 = 2 MiB scratch

    target_gemm<<<BB / 8, 256, 0, stream>>>(tf, W, tgt);
    attn<<<BB, 512, 0, stream>>>(nf, nl, mask, tgt, out);
}

// Round 8
// 185.326 us; speedup vs baseline: 5.3385x; 1.2673x over previous
//
#include <hip/hip_runtime.h>
#include <math.h>

#define BB   4096
#define KK   200
#define DD   128
#define FDIM 1024
#define MASK_FILL (-4294967295.0f)   // -(2^32)+1, as fp32

typedef float fx4 __attribute__((ext_vector_type(4)));

// ---------------- Kernel 1: target = target_feats @ W^T  ([B,FD] x [D,FD] -> [B,D])
__global__ __launch_bounds__(256) void target_gemm(const float* __restrict__ tf,
                                                   const float* __restrict__ W,
                                                   float* __restrict__ tgt) {
    __shared__ float s_tf[8 * FDIM];        // 32 KiB
    __shared__ float s_red[8][DD];          // 4 KiB
    const int tid = threadIdx.x;
    const int d   = tid & 127;
    const int h   = tid >> 7;               // 0/1: which half of FD (uniform per wave)
    const size_t r0 = (size_t)blockIdx.x * 8;

    const fx4* src = (const fx4*)(tf + r0 * FDIM);
    for (int i = tid; i < 8 * FDIM / 4; i += 256)
        ((fx4*)s_tf)[i] = src[i];
    __syncthreads();

    float acc[8] = {0, 0, 0, 0, 0, 0, 0, 0};
    const fx4* wr = (const fx4*)(W + (size_t)d * FDIM) + h * (FDIM / 8);
    #pragma unroll 4
    for (int i = 0; i < FDIM / 8; ++i) {
        fx4 w = wr[i];
        #pragma unroll
        for (int r = 0; r < 8; ++r) {
            fx4 t = ((const fx4*)(s_tf + r * FDIM + h * (FDIM / 2)))[i];  // wave-broadcast
            acc[r] += w.x * t.x + w.y * t.y + w.z * t.z + w.w * t.w;
        }
    }
    if (h == 1) {
        #pragma unroll
        for (int r = 0; r < 8; ++r) s_red[r][d] = acc[r];
    }
    __syncthreads();
    if (h == 0) {
        #pragma unroll
        for (int r = 0; r < 8; ++r)
            tgt[(r0 + r) * DD + d] = acc[r] + s_red[r][d];
    }
}

// ---------------- Kernel 2: one WAVE per batch row. Single pass over k with
// online softmax (flash-style). Lanes 0-31 process even k, lanes 32-63 odd k;
// one wave load instruction covers rows k,k+1 contiguously (1 KiB). No LDS,
// no barriers; nf and nl each read from HBM exactly once (nontemporal).
__global__ __launch_bounds__(256) void attn_online(const float* __restrict__ nf,
                                                   const float* __restrict__ nl,
                                                   const int*   __restrict__ mask,
                                                   const float* __restrict__ tgt,
                                                   float* __restrict__ out) {
    const int tid  = threadIdx.x;
    const int lane = tid & 63;
    const int l32  = lane & 31;          // fx4 column within a row (d = 4*l32)
    const int h    = (lane >> 5) & 1;    // half: 0 -> even k, 1 -> odd k
    const int b    = __builtin_amdgcn_readfirstlane(blockIdx.x * 4 + (tid >> 6));

    const fx4* nf4 = (const fx4*)(nf + (size_t)b * KK * DD);
    const fx4* nl4 = (const fx4*)(nl + (size_t)b * KK * DD);
    const int* mb  = mask + (size_t)b * KK;
    const fx4  tg  = ((const fx4*)(tgt + (size_t)b * DD))[l32];

    float m = -INFINITY, s = 0.0f;
    fx4 an = {0, 0, 0, 0}, al = {0, 0, 0, 0};

    for (int c = 0; c < 20; ++c) {       // 20 chunks x 10 k (5 pairs)
        fx4 vn[5], vl[5];
        #pragma unroll
        for (int j = 0; j < 5; ++j) {
            const int idx = (c * 5 + j) * 64 + lane;   // rows 2(c*5+j)+h, col l32
            vn[j] = __builtin_nontemporal_load(nf4 + idx);
            vl[j] = __builtin_nontemporal_load(nl4 + idx);
        }
        float a[5];
        #pragma unroll
        for (int j = 0; j < 5; ++j) {
            float d = vn[j].x * tg.x + vn[j].y * tg.y + vn[j].z * tg.z + vn[j].w * tg.w;
            #pragma unroll
            for (int off = 16; off > 0; off >>= 1)   // stays within 32-lane halves
                d += __shfl_xor(d, off);
            const int k0 = (c * 5 + j) * 2;
            const int mk = h ? mb[k0 + 1] : mb[k0];  // scalar loads, vector select
            a[j] = (mk > 0) ? d : MASK_FILL;
        }
        const float mc = fmaxf(fmaxf(fmaxf(a[0], a[1]), fmaxf(a[2], a[3])), a[4]);
        const float mn = fmaxf(m, mc);
        const float r  = __expf(m - mn);             // exp(-inf)=0 on first chunk
        m = mn;
        s *= r; an *= r; al *= r;
        #pragma unroll
        for (int j = 0; j < 5; ++j) {
            const float p = __expf(a[j] - m);        // p <= 1 always
            s  += p;
            an += p * vn[j];
            al += p * vl[j];
        }
    }

    // ---- merge the two 32-lane halves (even-k state <-> odd-k state)
    const float mo = __shfl_xor(m, 32);
    const float so = __shfl_xor(s, 32);
    fx4 ano, alo;
    ano.x = __shfl_xor(an.x, 32); ano.y = __shfl_xor(an.y, 32);
    ano.z = __shfl_xor(an.z, 32); ano.w = __shfl_xor(an.w, 32);
    alo.x = __shfl_xor(al.x, 32); alo.y = __shfl_xor(al.y, 32);
    alo.z = __shfl_xor(al.z, 32); alo.w = __shfl_xor(al.w, 32);
    const float mt  = fmaxf(m, mo);
    const float eL  = __expf(m - mt);
    const float eO  = __expf(mo - mt);
    const float inv = 1.0f / (s * eL + so * eO);

    if (h == 0) {
        fx4 r = (an * eL + ano * eO) * inv;          // neighbor_embd
        __builtin_nontemporal_store(r, &((fx4*)(out + (size_t)b * DD))[l32]);
    } else {
        fx4 r = (al * eL + alo * eO) * inv;          // label_embd
        __builtin_nontemporal_store(r, &((fx4*)(out + (size_t)BB * DD + (size_t)b * DD))[l32]);
    }
}

extern "C" void kernel_launch(void* const* d_in, const int* in_sizes, int n_in,
                              void* d_out, int out_size, void* d_ws, size_t ws_size,
                              hipStream_t stream) {
    const float* tf   = (const float*)d_in[0];
    const float* nf   = (const float*)d_in[1];
    const float* nl   = (const float*)d_in[2];
    const int*   mask = (const int*)d_in[3];
    const float* W    = (const float*)d_in[4];
    float* out = (float*)d_out;
    float* tgt = (float*)d_ws;                 // B*D*4 = 2 MiB scratch

    target_gemm<<<BB / 8, 256, 0, stream>>>(tf, W, tgt);
    attn_online<<<BB / 4, 256, 0, stream>>>(nf, nl, mask, tgt, out);
}

// Round 9
// 173.505 us; speedup vs baseline: 5.7022x; 1.0681x over previous
//
#include <hip/hip_runtime.h>
#include <math.h>

#define BB   4096
#define KK   200
#define DD   128
#define FDIM 1024
#define MASK_FILL (-4294967295.0f)   // -(2^32)+1, as fp32

typedef float fx4 __attribute__((ext_vector_type(4)));

// ---------------- Kernel 1: target = target_feats @ W^T  ([B,FD] x [D,FD] -> [B,D])
__global__ __launch_bounds__(256) void target_gemm(const float* __restrict__ tf,
                                                   const float* __restrict__ W,
                                                   float* __restrict__ tgt) {
    __shared__ float s_tf[8 * FDIM];        // 32 KiB
    __shared__ float s_red[8][DD];          // 4 KiB
    const int tid = threadIdx.x;
    const int d   = tid & 127;
    const int h   = tid >> 7;               // 0/1: which half of FD (uniform per wave)
    const size_t r0 = (size_t)blockIdx.x * 8;

    const fx4* src = (const fx4*)(tf + r0 * FDIM);
    for (int i = tid; i < 8 * FDIM / 4; i += 256)
        ((fx4*)s_tf)[i] = src[i];
    __syncthreads();

    float acc[8] = {0, 0, 0, 0, 0, 0, 0, 0};
    const fx4* wr = (const fx4*)(W + (size_t)d * FDIM) + h * (FDIM / 8);
    #pragma unroll 4
    for (int i = 0; i < FDIM / 8; ++i) {
        fx4 w = wr[i];
        #pragma unroll
        for (int r = 0; r < 8; ++r) {
            fx4 t = ((const fx4*)(s_tf + r * FDIM + h * (FDIM / 2)))[i];  // wave-broadcast
            acc[r] += w.x * t.x + w.y * t.y + w.z * t.z + w.w * t.w;
        }
    }
    if (h == 1) {
        #pragma unroll
        for (int r = 0; r < 8; ++r) s_red[r][d] = acc[r];
    }
    __syncthreads();
    if (h == 0) {
        #pragma unroll
        for (int r = 0; r < 8; ++r)
            tgt[(r0 + r) * DD + d] = acc[r] + s_red[r][d];
    }
}

// ---------------- Kernel 2: TWO waves per batch row (k 0..99 / 100..199), one
// pass, online softmax. Within a wave: lanes 0-31 even k, lanes 32-63 odd k.
// Chunks of 2 row-pairs (4 loads in flight) keep VGPR <= 64 so 8 waves/SIMD
// (32 waves/CU) hide HBM latency. One LDS merge + single barrier at the end.
__global__ __launch_bounds__(256, 8) void attn_online(const float* __restrict__ nf,
                                                      const float* __restrict__ nl,
                                                      const int*   __restrict__ mask,
                                                      const float* __restrict__ tgt,
                                                      float* __restrict__ out) {
    __shared__ float s_m[2][2], s_s[2][2];
    __shared__ fx4   s_an[2][2][32];     // [bloc][w][col]
    __shared__ fx4   s_al[2][2][32];

    const int tid  = threadIdx.x;
    const int lane = tid & 63;
    const int l32  = lane & 31;          // fx4 column (d = 4*l32)
    const int h    = (lane >> 5) & 1;    // parity half: 0 -> even k, 1 -> odd k
    const int bloc = tid >> 7;           // which of the block's 2 batch rows
    const int b    = __builtin_amdgcn_readfirstlane(blockIdx.x * 2 + bloc);
    const int w    = __builtin_amdgcn_readfirstlane((tid >> 6) & 1);  // k-range half

    const fx4* nf4 = (const fx4*)(nf + (size_t)b * KK * DD) + (size_t)w * 50 * 64;
    const fx4* nl4 = (const fx4*)(nl + (size_t)b * KK * DD) + (size_t)w * 50 * 64;
    const int* mb  = mask + (size_t)b * KK + w * 100;
    const fx4  tg  = ((const fx4*)(tgt + (size_t)b * DD))[l32];

    float m = -INFINITY, s = 0.0f;
    fx4 an = {0, 0, 0, 0}, al = {0, 0, 0, 0};

    for (int c = 0; c < 25; ++c) {       // 25 chunks x 2 pairs (4 k) per wave
        fx4 vn[2], vl[2];
        #pragma unroll
        for (int j = 0; j < 2; ++j) {
            const int idx = (c * 2 + j) * 64 + lane;   // rows 4c+2j+h, col l32
            vn[j] = __builtin_nontemporal_load(nf4 + idx);
            vl[j] = __builtin_nontemporal_load(nl4 + idx);
        }
        float a[2];
        #pragma unroll
        for (int j = 0; j < 2; ++j) {
            float d = vn[j].x * tg.x + vn[j].y * tg.y + vn[j].z * tg.z + vn[j].w * tg.w;
            #pragma unroll
            for (int off = 16; off > 0; off >>= 1)   // stays within 32-lane halves
                d += __shfl_xor(d, off);
            const int k0 = c * 4 + 2 * j;
            const int mk = h ? mb[k0 + 1] : mb[k0];  // scalar loads, vector select
            a[j] = (mk > 0) ? d : MASK_FILL;
        }
        const float mn = fmaxf(m, fmaxf(a[0], a[1]));
        const float r  = __expf(m - mn);             // exp(-inf)=0 on first chunk
        m = mn;
        s *= r; an *= r; al *= r;
        #pragma unroll
        for (int j = 0; j < 2; ++j) {
            const float p = __expf(a[j] - m);        // p <= 1 always
            s  += p;
            an += p * vn[j];
            al += p * vl[j];
        }
    }

    // ---- intra-wave merge: even-k state <-> odd-k state (all lanes end up full)
    {
        const float mo = __shfl_xor(m, 32);
        const float so = __shfl_xor(s, 32);
        fx4 ano, alo;
        ano.x = __shfl_xor(an.x, 32); ano.y = __shfl_xor(an.y, 32);
        ano.z = __shfl_xor(an.z, 32); ano.w = __shfl_xor(an.w, 32);
        alo.x = __shfl_xor(al.x, 32); alo.y = __shfl_xor(al.y, 32);
        alo.z = __shfl_xor(al.z, 32); alo.w = __shfl_xor(al.w, 32);
        const float mt = fmaxf(m, mo);
        const float e0 = __expf(m - mt);
        const float e1 = __expf(mo - mt);
        s  = s * e0 + so * e1;
        an = an * e0 + ano * e1;
        al = al * e0 + alo * e1;
        m  = mt;
    }

    // ---- cross-wave merge (k-range halves) via LDS, one barrier
    if (h == 0) s_an[bloc][w][l32] = an; else s_al[bloc][w][l32] = al;
    if (lane == 0) { s_m[bloc][w] = m; s_s[bloc][w] = s; }
    __syncthreads();

    if (w == 0) {
        const float m1 = s_m[bloc][1];
        const float s1 = s_s[bloc][1];
        const fx4 mine  = (h == 0) ? an : al;
        const fx4 other = (h == 0) ? s_an[bloc][1][l32] : s_al[bloc][1][l32];
        const float M   = fmaxf(m, m1);
        const float e0  = __expf(m - M);
        const float e1  = __expf(m1 - M);
        const float inv = 1.0f / (s * e0 + s1 * e1);
        const fx4 r = (mine * e0 + other * e1) * inv;
        if (h == 0)
            __builtin_nontemporal_store(r, &((fx4*)(out + (size_t)b * DD))[l32]);
        else
            __builtin_nontemporal_store(r, &((fx4*)(out + (size_t)BB * DD + (size_t)b * DD))[l32]);
    }
}

extern "C" void kernel_launch(void* const* d_in, const int* in_sizes, int n_in,
                              void* d_out, int out_size, void* d_ws, size_t ws_size,
                              hipStream_t stream) {
    const float* tf   = (const float*)d_in[0];
    const float* nf   = (const float*)d_in[1];
    const float* nl   = (const float*)d_in[2];
    const int*   mask = (const int*)d_in[3];
    const float* W    = (const float*)d_in[4];
    float* out = (float*)d_out;
    float* tgt = (float*)d_ws;                 // B*D*4 = 2 MiB scratch

    target_gemm<<<BB / 8, 256, 0, stream>>>(tf, W, tgt);
    attn_online<<<BB / 2, 256, 0, stream>>>(nf, nl, mask, tgt, out);
}